// Round 10
// baseline (175.440 us; speedup 1.0000x reference)
//
#include <hip/hip_runtime.h>
#include <hip/hip_bf16.h>
#include <math.h>

#define GN 12288
#define GE 196608
#define GK 1433
#define GC 32
#define CAP 64        // fixed CSR capacity/node; max degree ~38 (12-sigma under 64)
#define BSTR 136      // bf16 stride for B tiles
#define NSPLIT 12
#define KCHUNK 128    // 12*128 = 1536 >= 1433
#define GEMMB (96 * NSPLIT)   // 1152 gemm blocks
#define EDGEB 768             // 768*256 = 196608 = GE exactly

typedef __attribute__((ext_vector_type(8))) short bf16x8;
typedef __attribute__((ext_vector_type(4))) float f32x4;

static __device__ inline unsigned short f2bf(float f) {
    unsigned u = __float_as_uint(f);
    unsigned r = (u + 0x7fffu + ((u >> 16) & 1u)) >> 16;
    return (unsigned short)r;
}
static __device__ inline float bf2f(unsigned short h) {
    return __uint_as_float(((unsigned)h) << 16);
}

// ---------------- fused: gemm (blocks 0..GEMMB) + graph build (blocks GEMMB..) ----
// gemm: whole 128-k slab hoisted to registers (64 dword loads in flight), then
// convert + 12 MFMAs from regs; B staged once in LDS under the load shadow.
__global__ __launch_bounds__(256) void fused_kernel(const float* __restrict__ x,
                                                    const float* __restrict__ W1,
                                                    const int* __restrict__ ei,
                                                    float* __restrict__ xw,
                                                    unsigned* __restrict__ cnt,
                                                    unsigned* __restrict__ deg,
                                                    unsigned* __restrict__ adjF) {
    int t = threadIdx.x, bid = blockIdx.x;

    if (bid >= GEMMB) {
        // ---- graph build: one edge per thread ----
        int e = (bid - GEMMB) * 256 + t;
        int src = ei[e];
        int dst = ei[GE + e];
        unsigned pos = atomicAdd(&cnt[src], 1u);
        if (pos < CAP) adjF[(unsigned)src * CAP + pos] = (unsigned)dst;
        atomicAdd(&deg[dst], 1u);
        return;
    }

    __shared__ unsigned short Bh[32 * BSTR], Bl[32 * BSTR];
    int lane = t & 63, w = t >> 6;
    int quad = lane >> 4, l15 = lane & 15;
    int row0 = (bid % 96) * 128;
    int ks = bid / 96;
    int k0 = ks * KCHUNK;
    int kend = min(GK, k0 + KCHUNK);
    const float* xr0 = x + (size_t)(row0 + w * 32 + l15) * GK;
    const float* xr1 = xr0 + 16 * GK;

    // ---- hoist ALL x loads: 2 rows x 4 iters x 8 floats = 64 dword loads in flight
    float a0[4][8], a1[4][8];
    #pragma unroll
    for (int it = 0; it < 4; ++it) {
        int kq = k0 + it * 32 + quad * 8;
        if (kq + 8 <= kend) {
            #pragma unroll
            for (int j = 0; j < 8; ++j) { a0[it][j] = xr0[kq + j]; a1[it][j] = xr1[kq + j]; }
        } else {
            #pragma unroll
            for (int j = 0; j < 8; ++j) {
                bool v = (kq + j) < kend;
                a0[it][j] = v ? xr0[kq + j] : 0.f;
                a1[it][j] = v ? xr1[kq + j] : 0.f;
            }
        }
    }

    // ---- stage B (whole 128-k chunk) under the x-load shadow ----
    #pragma unroll
    for (int e = 0; e < 16; ++e) {
        int idx = e * 256 + t;
        int kk = idx >> 5, c = idx & 31;
        int kg = k0 + kk;
        float f = (kg < kend) ? W1[(size_t)kg * GC + c] : 0.f;
        unsigned short hh = f2bf(f);
        unsigned short ll = f2bf(f - bf2f(hh));
        Bh[c * BSTR + kk] = hh;
        Bl[c * BSTR + kk] = ll;
    }
    __syncthreads();

    // ---- convert + MFMA, all from registers/LDS ----
    f32x4 acc[2][2] = {};
    #pragma unroll
    for (int it = 0; it < 4; ++it) {
        bf16x8 ah[2], al[2];
        #pragma unroll
        for (int j = 0; j < 8; ++j) {
            unsigned short h0 = f2bf(a0[it][j]);
            ah[0][j] = (short)h0; al[0][j] = (short)f2bf(a0[it][j] - bf2f(h0));
            unsigned short h1 = f2bf(a1[it][j]);
            ah[1][j] = (short)h1; al[1][j] = (short)f2bf(a1[it][j] - bf2f(h1));
        }
        bf16x8 bh[2], bl_[2];
        #pragma unroll
        for (int nt = 0; nt < 2; ++nt) {
            int c = nt * 16 + l15;
            bh[nt]  = *(bf16x8*)&Bh[c * BSTR + it * 32 + quad * 8];
            bl_[nt] = *(bf16x8*)&Bl[c * BSTR + it * 32 + quad * 8];
        }
        #pragma unroll
        for (int mt = 0; mt < 2; ++mt)
            #pragma unroll
            for (int nt = 0; nt < 2; ++nt) {
                acc[mt][nt] = __builtin_amdgcn_mfma_f32_16x16x32_bf16(ah[mt], bh[nt],  acc[mt][nt], 0, 0, 0);
                acc[mt][nt] = __builtin_amdgcn_mfma_f32_16x16x32_bf16(ah[mt], bl_[nt], acc[mt][nt], 0, 0, 0);
                acc[mt][nt] = __builtin_amdgcn_mfma_f32_16x16x32_bf16(al[mt], bh[nt],  acc[mt][nt], 0, 0, 0);
            }
    }
    #pragma unroll
    for (int mt = 0; mt < 2; ++mt)
        #pragma unroll
        for (int i = 0; i < 4; ++i) {
            int row = row0 + w * 32 + mt * 16 + quad * 4 + i;
            float* po = xw + (size_t)row * GC;
            atomicAdd(&po[l15], acc[mt][0][i]);
            atomicAdd(&po[16 + l15], acc[mt][1][i]);
        }
}

// ---------------- GCN gather -> h (inline rsqrt of deg) ----------------
__global__ __launch_bounds__(256) void gcn_kernel(const float* __restrict__ xw,
                                                  const unsigned* __restrict__ deg,
                                                  const unsigned* __restrict__ cnt,
                                                  const unsigned* __restrict__ adjF,
                                                  const float* __restrict__ b1,
                                                  float* __restrict__ h) {
    int w = threadIdx.x >> 6;
    int lane = threadIdx.x & 63;
    int i = blockIdx.x * 4 + w;
    int f = lane & 31, half = lane >> 5;
    unsigned cl = min(cnt[i], (unsigned)CAP);
    const unsigned* ai = adjF + (unsigned)i * CAP;
    float acc = 0.f;
    for (unsigned j = half; j < cl; j += 8) {
        unsigned lim = cl - 1;
        unsigned j1 = j + 2, j2 = j + 4, j3 = j + 6;
        unsigned d0 = ai[j];
        unsigned d1 = ai[min(j1, lim)];
        unsigned d2 = ai[min(j2, lim)];
        unsigned d3 = ai[min(j3, lim)];
        float m1 = j1 < cl ? 1.f : 0.f;
        float m2 = j2 < cl ? 1.f : 0.f;
        float m3 = j3 < cl ? 1.f : 0.f;
        acc += xw[(size_t)d0 * GC + f] * rsqrtf((float)(deg[d0] + 1u));
        acc += m1 * xw[(size_t)d1 * GC + f] * rsqrtf((float)(deg[d1] + 1u));
        acc += m2 * xw[(size_t)d2 * GC + f] * rsqrtf((float)(deg[d2] + 1u));
        acc += m3 * xw[(size_t)d3 * GC + f] * rsqrtf((float)(deg[d3] + 1u));
    }
    acc += __shfl_xor(acc, 32, 64);
    float disi = rsqrtf((float)(deg[i] + 1u));
    float v = b1[f] + disi * (disi * xw[(size_t)i * GC + f] + acc);
    if (half == 0) h[(size_t)i * GC + f] = fmaxf(v, 0.f);
}

// ---------------- SAGE gather + fused head ----------------
__global__ __launch_bounds__(256) void sage_kernel(const float* __restrict__ h,
                                                   const unsigned* __restrict__ cnt,
                                                   const unsigned* __restrict__ adjF,
                                                   const float* __restrict__ Wl,
                                                   const float* __restrict__ bl,
                                                   const float* __restrict__ Wr,
                                                   const float* __restrict__ br,
                                                   const float* __restrict__ W3,
                                                   const float* __restrict__ b3,
                                                   float* __restrict__ out) {
    __shared__ float sh[4][64];
    __shared__ float so[4][16];
    int w = threadIdx.x >> 6, lane = threadIdx.x & 63;
    int i = blockIdx.x * 4 + w;
    int f = lane & 31, half = lane >> 5;
    unsigned ci = cnt[i];
    unsigned cl = min(ci, (unsigned)CAP);
    const unsigned* ai = adjF + (unsigned)i * CAP;
    float acc = 0.f;
    for (unsigned j = half; j < cl; j += 8) {
        unsigned lim = cl - 1;
        unsigned j1 = j + 2, j2 = j + 4, j3 = j + 6;
        unsigned d0 = ai[j];
        unsigned d1 = ai[min(j1, lim)];
        unsigned d2 = ai[min(j2, lim)];
        unsigned d3 = ai[min(j3, lim)];
        float m1 = j1 < cl ? 1.f : 0.f;
        float m2 = j2 < cl ? 1.f : 0.f;
        float m3 = j3 < cl ? 1.f : 0.f;
        acc += h[(size_t)d0 * GC + f];
        acc += m1 * h[(size_t)d1 * GC + f];
        acc += m2 * h[(size_t)d2 * GC + f];
        acc += m3 * h[(size_t)d3 * GC + f];
    }
    acc += __shfl_xor(acc, 32, 64);
    float agg = ci ? acc / (float)ci : 0.f;
    float hv = h[(size_t)i * GC + f];
    if (half == 0) { sh[w][f] = hv; sh[w][32 + f] = agg; }
    __syncthreads();
    int c = lane;
    float hid = 0.f;
    if (c < 16) {
        hid = bl[c] + br[c];
        #pragma unroll
        for (int ff = 0; ff < 32; ++ff)
            hid += sh[w][ff] * Wl[ff * 16 + c] + sh[w][32 + ff] * Wr[ff * 16 + c];
        hid = fmaxf(hid, 0.f);
    }
    float n2 = hid * hid;
    n2 += __shfl_xor(n2, 1, 64);
    n2 += __shfl_xor(n2, 2, 64);
    n2 += __shfl_xor(n2, 4, 64);
    n2 += __shfl_xor(n2, 8, 64);
    float o = hid / (sqrtf(n2) + 1e-6f);
    if (c < 16) so[w][c] = o;
    __syncthreads();
    float logit = -INFINITY;
    if (lane < 7) {
        logit = b3[lane];
        #pragma unroll
        for (int cc = 0; cc < 16; ++cc) logit += so[w][cc] * W3[cc * 7 + lane];
    }
    float m = logit;
    m = fmaxf(m, __shfl_xor(m, 1, 64));
    m = fmaxf(m, __shfl_xor(m, 2, 64));
    m = fmaxf(m, __shfl_xor(m, 4, 64));
    float e = expf(logit - m);
    float s = e;
    s += __shfl_xor(s, 1, 64);
    s += __shfl_xor(s, 2, 64);
    s += __shfl_xor(s, 4, 64);
    if (lane < 7) out[(size_t)i * 7 + lane] = e / s;
}

extern "C" void kernel_launch(void* const* d_in, const int* in_sizes, int n_in,
                              void* d_out, int out_size, void* d_ws, size_t ws_size,
                              hipStream_t stream) {
    const float* x  = (const float*)d_in[0];
    const int*   ei = (const int*)d_in[1];
    const float* W1 = (const float*)d_in[2];
    const float* b1 = (const float*)d_in[3];
    const float* Wl = (const float*)d_in[4];
    const float* bl = (const float*)d_in[5];
    const float* Wr = (const float*)d_in[6];
    const float* br = (const float*)d_in[7];
    const float* W3 = (const float*)d_in[8];
    const float* b3 = (const float*)d_in[9];
    float* out = (float*)d_out;

    char* ws = (char*)d_ws;
    const size_t S = (size_t)GN * GC * 4;                 // 1.57 MB
    // zero region: [xw | cnt | deg] contiguous -> one memset
    float*    xw   = (float*)(ws);
    unsigned* cnt  = (unsigned*)(ws + S);
    unsigned* deg  = cnt + GN;
    float*    h    = (float*)((char*)(deg + GN));
    unsigned* adjF = (unsigned*)((char*)h + S);           // GN*CAP*4 = 3 MB

    hipMemsetAsync(ws, 0, S + 2 * (size_t)GN * 4, stream);
    fused_kernel<<<GEMMB + EDGEB, 256, 0, stream>>>(x, W1, ei, xw, cnt, deg, adjF);
    gcn_kernel<<<GN / 4, 256, 0, stream>>>(xw, deg, cnt, adjF, b1, h);
    sage_kernel<<<GN / 4, 256, 0, stream>>>(h, cnt, adjF, Wl, bl, Wr, br, W3, b3, out);
}